// Round 3
// baseline (421.914 us; speedup 1.0000x reference)
//
#include <hip/hip_runtime.h>

// ---------------- types ----------------
using u16    = unsigned short;
using u32    = unsigned int;
using bf16x8 = __attribute__((ext_vector_type(8))) __bf16;
using f32x4  = __attribute__((ext_vector_type(4))) float;
using u16x4  = __attribute__((ext_vector_type(4))) u16;
using u16x8  = __attribute__((ext_vector_type(8))) u16;

__device__ __forceinline__ u16 f32_to_bf16(float f) {
    u32 u = __float_as_uint(f);
    u32 r = (u + 0x7FFFu + ((u >> 16) & 1u)) >> 16;  // RNE
    return (u16)r;
}

// async global->LDS, 16B per lane (literal size required)
__device__ __forceinline__ void gld_lds16(const void* g, void* l) {
    __builtin_amdgcn_global_load_lds(
        (const __attribute__((address_space(1))) u32*)g,
        (__attribute__((address_space(3))) u32*)l,
        16, 0, 0);
}

// Cl(3,0) reorder sign for e_a * e_b (metric all +1)
__device__ __forceinline__ float cl3_sign(int a, int b) {
    int swaps = __popc((a >> 1) & b) + __popc((a >> 2) & b);
    return (swaps & 1) ? -1.0f : 1.0f;
}

// ---------------- prep: out[0] = x (fp32 copy), A0 = bf16(x) ----------------
__global__ __launch_bounds__(256) void prep_kernel(
    const float* __restrict__ x, float* __restrict__ out0, u16* __restrict__ A0)
{
    const int t = blockIdx.x * 256 + threadIdx.x;
    const float4 v = reinterpret_cast<const float4*>(x)[t];
    reinterpret_cast<float4*>(out0)[t] = v;
    u16x4 b;
    b.x = f32_to_bf16(v.x);
    b.y = f32_to_bf16(v.y);
    b.z = f32_to_bf16(v.z);
    b.w = f32_to_bf16(v.w);
    reinterpret_cast<u16x4*>(A0)[t] = b;
}

// ---------------- expand: Wmat[(o*8+k)*4096 + i*8+p] = sign(p,p^k)*w[o][i][p^k] ----------------
__device__ __forceinline__ void expand_body(
    const float* __restrict__ w, u16* __restrict__ Wm, int t)
{
    const int o = t >> 9;
    const int i = t & 511;
    const float* src = w + ((size_t)t << 3);
    const float4 w0 = reinterpret_cast<const float4*>(src)[0];
    const float4 w1 = reinterpret_cast<const float4*>(src)[1];
    const float wv[8] = {w0.x, w0.y, w0.z, w0.w, w1.x, w1.y, w1.z, w1.w};
    #pragma unroll
    for (int kb = 0; kb < 8; ++kb) {
        u16x8 ov;
        #pragma unroll
        for (int p = 0; p < 8; ++p) {
            const int q = p ^ kb;
            ov[p] = f32_to_bf16(cl3_sign(p, q) * wv[q]);
        }
        reinterpret_cast<u16x8*>(Wm)[((size_t)(o * 8 + kb) << 9) + i] = ov;
    }
}

// all three weights in ONE dispatch (3 x 1024 blocks)
__global__ __launch_bounds__(256) void expand3_kernel(
    const float* __restrict__ wa, const float* __restrict__ wb,
    const float* __restrict__ wc,
    u16* __restrict__ Wa, u16* __restrict__ Wb, u16* __restrict__ Wc)
{
    const int bb = blockIdx.x;           // 0..3071
    const int Lw = bb >> 10;
    const float* w = (Lw == 0) ? wa : (Lw == 1) ? wb : wc;
    u16* Wm       = (Lw == 0) ? Wa : (Lw == 1) ? Wb : Wc;
    expand_body(w, Wm, (bb & 1023) * 256 + threadIdx.x);
}

// single-weight fallback (small ws)
__global__ __launch_bounds__(256) void expand_kernel(
    const float* __restrict__ w, u16* __restrict__ Wm)
{
    expand_body(w, Wm, blockIdx.x * 256 + threadIdx.x);
}

// ---------------- GEMM: 2-phase/K-tile, counted vmcnt, 128x256 tile, BK=64 ----------------
// C[2048,4096] = A[2048,4096] x Bt[4096,4096]^T; grid 16x16 = 256 blocks (1/CU).
// 8 waves (2M x 4N), 64x64 per wave, 16x16x32 bf16 MFMA (4x4 frags x 2 k-slices).
// Phase 0: read A01 + ALL B frags (B held in regs), 16 MFMA.
// Phase 1: read A23 only, reuse B regs, 16 MFMA.  4 barriers/K-tile (was 8).
// Tri-buffered LDS (3 x 48KB), prefetch depth 2, steady-state vmcnt(6).
constexpr int BM = 128, BN = 256, BK = 64, KDIM = 4096, NKT = KDIM / BK;
constexpr int ASZ = BM * BK;        // 8192 u16
constexpr int BSZ = BN * BK;        // 16384 u16
constexpr int BUF = ASZ + BSZ;      // 24576 u16 = 48KB

__global__ __launch_bounds__(512, 2) void gemm8_kernel(
    const u16* __restrict__ A,   // [2048,4096] bf16 row-major
    const u16* __restrict__ Bt,  // [4096,4096] bf16, row n = output col
    float*     __restrict__ C,   // [2048,4096] fp32
    u16*       __restrict__ An)  // [2048,4096] bf16 or nullptr
{
    __shared__ __attribute__((aligned(16))) u16 lds[3 * BUF];  // 144KB

    const int tid = threadIdx.x;
    const int l   = tid & 63;
    const int w   = tid >> 6;        // wave 0..7
    const int wr  = w >> 2;          // 0..1
    const int wc  = w & 3;           // 0..3
    const int l8  = l >> 3, l7 = l & 7;
    const int fr  = l & 15, fq = l >> 4;
    const int row0 = blockIdx.y * BM;
    const int col0 = blockIdx.x * BN;

    // ---- staging: one gld_lds = one wave's 8-row group (1KB); T2 swizzle via
    // pre-swizzled GLOBAL source, LDS destination stays linear (rule #21) ----
    auto stageA = [&](int buf, int kt, int q) {   // q in {0,1}
        const int r = (q * 8 + w) * 8 + l8;       // tile row 0..127 (r&7 == l8)
        const u16* src = A + (size_t)(row0 + r) * KDIM + kt + ((l7 ^ l8) << 3);
        gld_lds16(src, &lds[buf * BUF + r * BK + l7 * 8]);
    };
    auto stageB = [&](int buf, int kt, int q) {   // q in {0..3}
        const int r = (q * 8 + w) * 8 + l8;       // tile col 0..255
        const u16* src = Bt + (size_t)(col0 + r) * KDIM + kt + ((l7 ^ l8) << 3);
        gld_lds16(src, &lds[buf * BUF + ASZ + r * BK + l7 * 8]);
    };
    // ---- swizzled fragment reads ----
    auto rdA = [&](int buf, int mi, int ks) -> bf16x8 {
        const int r = wr * 64 + mi * 16 + fr;
        const int c = (ks * 4 + fq) ^ (r & 7);
        return *reinterpret_cast<const bf16x8*>(&lds[buf * BUF + r * BK + c * 8]);
    };
    auto rdB = [&](int buf, int ni, int ks) -> bf16x8 {
        const int r = wc * 64 + ni * 16 + fr;
        const int c = (ks * 4 + fq) ^ (r & 7);
        return *reinterpret_cast<const bf16x8*>(&lds[buf * BUF + ASZ + r * BK + c * 8]);
    };

    f32x4 acc[4][4];
    #pragma unroll
    for (int i = 0; i < 4; ++i)
        #pragma unroll
        for (int j = 0; j < 4; ++j)
            acc[i][j] = f32x4{0.f, 0.f, 0.f, 0.f};

    // ---- prologue: stage tiles 0 and 1 (6 loads each) ----
    stageA(0, 0, 0); stageA(0, 0, 1);
    stageB(0, 0, 0); stageB(0, 0, 1); stageB(0, 0, 2); stageB(0, 0, 3);
    stageA(1, BK, 0); stageA(1, BK, 1);
    stageB(1, BK, 0); stageB(1, BK, 1); stageB(1, BK, 2); stageB(1, BK, 3);
    asm volatile("s_waitcnt vmcnt(6)" ::: "memory");   // tile0 landed
    __builtin_amdgcn_s_barrier();

    bf16x8 a[2][2], b[4][2];

    int cb = 0, nb = 2;
    for (int t = 0; t < NKT; ++t) {
        const int kt2 = (t + 2) * BK;
        const bool pre = (t + 2 < NKT);

        // ---- phase 0: A rows 0-1, all B; 16 MFMA ----
        #pragma unroll
        for (int mi = 0; mi < 2; ++mi)
            #pragma unroll
            for (int ks = 0; ks < 2; ++ks) a[mi][ks] = rdA(cb, mi, ks);
        #pragma unroll
        for (int ni = 0; ni < 4; ++ni)
            #pragma unroll
            for (int ks = 0; ks < 2; ++ks) b[ni][ks] = rdB(cb, ni, ks);
        if (pre) { stageA(nb, kt2, 0); stageA(nb, kt2, 1); stageB(nb, kt2, 0); }
        __builtin_amdgcn_s_barrier();
        asm volatile("s_waitcnt lgkmcnt(0)" ::: "memory");
        __builtin_amdgcn_sched_barrier(0);
        __builtin_amdgcn_s_setprio(1);
        #pragma unroll
        for (int mi = 0; mi < 2; ++mi)
            #pragma unroll
            for (int ni = 0; ni < 4; ++ni)
                #pragma unroll
                for (int ks = 0; ks < 2; ++ks)
                    acc[mi][ni] = __builtin_amdgcn_mfma_f32_16x16x32_bf16(
                        a[mi][ks], b[ni][ks], acc[mi][ni], 0, 0, 0);
        __builtin_amdgcn_s_setprio(0);
        __builtin_amdgcn_s_barrier();

        // ---- phase 1: A rows 2-3, reuse B regs; 16 MFMA ----
        #pragma unroll
        for (int mi = 0; mi < 2; ++mi)
            #pragma unroll
            for (int ks = 0; ks < 2; ++ks) a[mi][ks] = rdA(cb, mi + 2, ks);
        if (pre) { stageB(nb, kt2, 1); stageB(nb, kt2, 2); stageB(nb, kt2, 3); }
        __builtin_amdgcn_s_barrier();
        asm volatile("s_waitcnt lgkmcnt(0)" ::: "memory");
        __builtin_amdgcn_sched_barrier(0);
        __builtin_amdgcn_s_setprio(1);
        #pragma unroll
        for (int mi = 0; mi < 2; ++mi)
            #pragma unroll
            for (int ni = 0; ni < 4; ++ni)
                #pragma unroll
                for (int ks = 0; ks < 2; ++ks)
                    acc[mi + 2][ni] = __builtin_amdgcn_mfma_f32_16x16x32_bf16(
                        a[mi][ks], b[ni][ks], acc[mi + 2][ni], 0, 0, 0);
        __builtin_amdgcn_s_setprio(0);
        // end of iter: drain tile t+1's loads (keep t+2's 6 in flight)
        if (t + 2 < NKT)      { asm volatile("s_waitcnt vmcnt(6)" ::: "memory"); }
        else if (t + 1 < NKT) { asm volatile("s_waitcnt vmcnt(0)" ::: "memory"); }
        __builtin_amdgcn_s_barrier();

        cb = (cb == 2) ? 0 : cb + 1;
        nb = (nb == 2) ? 0 : nb + 1;
    }

    // ---- epilogue: C/D layout col = l&15, row = (l>>4)*4 + v ----
    #pragma unroll
    for (int mi = 0; mi < 4; ++mi) {
        #pragma unroll
        for (int v = 0; v < 4; ++v) {
            const int r = row0 + wr * 64 + mi * 16 + fq * 4 + v;
            const size_t base = ((size_t)r << 12) + col0 + wc * 64 + fr;
            #pragma unroll
            for (int ni = 0; ni < 4; ++ni)
                C[base + ni * 16] = acc[mi][ni][v];
            if (An != nullptr) {
                #pragma unroll
                for (int ni = 0; ni < 4; ++ni)
                    An[base + ni * 16] = f32_to_bf16(acc[mi][ni][v]);
            }
        }
    }
}

// ---------------- launcher ----------------
// fused ws layout: A0 | A1 | Wm0 | Wm1 | Wm2  (128 MiB total, bf16)
// fallback (ws < 128 MiB): A0 | A1 | Wm (67 MiB), per-layer expand
extern "C" void kernel_launch(void* const* d_in, const int* in_sizes, int n_in,
                              void* d_out, int out_size, void* d_ws, size_t ws_size,
                              hipStream_t stream) {
    const float* x = (const float*)d_in[0];
    const float* wts[3] = {(const float*)d_in[1], (const float*)d_in[2],
                           (const float*)d_in[3]};
    float* out = (float*)d_out;

    constexpr size_t LAYER = (size_t)2048 * 4096;   // activation elems
    constexpr size_t WSZ   = (size_t)4096 * 4096;   // Wmat elems

    u16* A0 = (u16*)d_ws;
    u16* A1 = A0 + LAYER;

    prep_kernel<<<dim3(8192), dim3(256), 0, stream>>>(x, out, A0);

    const bool fused = ws_size >= (2 * LAYER + 3 * WSZ) * sizeof(u16);
    u16* Ac = A0;
    u16* Anx = A1;

    if (fused) {
        u16* Wm[3] = {A1 + LAYER, A1 + LAYER + WSZ, A1 + LAYER + 2 * WSZ};
        expand3_kernel<<<dim3(3072), dim3(256), 0, stream>>>(
            wts[0], wts[1], wts[2], Wm[0], Wm[1], Wm[2]);
        for (int L = 0; L < 3; ++L) {
            gemm8_kernel<<<dim3(16, 16), dim3(512), 0, stream>>>(
                Ac, Wm[L], out + (size_t)(L + 1) * LAYER, (L == 2) ? nullptr : Anx);
            u16* t = Ac; Ac = Anx; Anx = t;
        }
    } else {
        u16* Wm = A1 + LAYER;
        for (int L = 0; L < 3; ++L) {
            expand_kernel<<<dim3(1024), dim3(256), 0, stream>>>(wts[L], Wm);
            gemm8_kernel<<<dim3(16, 16), dim3(512), 0, stream>>>(
                Ac, Wm, out + (size_t)(L + 1) * LAYER, (L == 2) ? nullptr : Anx);
            u16* t = Ac; Ac = Anx; Anx = t;
        }
    }
}

// Round 5
// 387.842 us; speedup vs baseline: 1.0879x; 1.0879x over previous
//
#include <hip/hip_runtime.h>

// ---------------- types ----------------
using u16    = unsigned short;
using u32    = unsigned int;
using bf16x8 = __attribute__((ext_vector_type(8))) __bf16;
using f32x4  = __attribute__((ext_vector_type(4))) float;
using u16x4  = __attribute__((ext_vector_type(4))) u16;
using u16x8  = __attribute__((ext_vector_type(8))) u16;

__device__ __forceinline__ u16 f32_to_bf16(float f) {
    u32 u = __float_as_uint(f);
    u32 r = (u + 0x7FFFu + ((u >> 16) & 1u)) >> 16;  // RNE
    return (u16)r;
}

// async global->LDS, 16B per lane (literal size required)
__device__ __forceinline__ void gld_lds16(const void* g, void* l) {
    __builtin_amdgcn_global_load_lds(
        (const __attribute__((address_space(1))) u32*)g,
        (__attribute__((address_space(3))) u32*)l,
        16, 0, 0);
}

// Cl(3,0) reorder sign for e_a * e_b (metric all +1)
__device__ __forceinline__ float cl3_sign(int a, int b) {
    int swaps = __popc((a >> 1) & b) + __popc((a >> 2) & b);
    return (swaps & 1) ? -1.0f : 1.0f;
}

// ---------------- prep: out[0] = x (fp32 copy), A0 = bf16(x) ----------------
__global__ __launch_bounds__(256) void prep_kernel(
    const float* __restrict__ x, float* __restrict__ out0, u16* __restrict__ A0)
{
    const int t = blockIdx.x * 256 + threadIdx.x;
    const float4 v = reinterpret_cast<const float4*>(x)[t];
    reinterpret_cast<float4*>(out0)[t] = v;
    u16x4 b;
    b.x = f32_to_bf16(v.x);
    b.y = f32_to_bf16(v.y);
    b.z = f32_to_bf16(v.z);
    b.w = f32_to_bf16(v.w);
    reinterpret_cast<u16x4*>(A0)[t] = b;
}

// ---------------- expand: Wmat[(o*8+k)*4096 + i*8+p] = sign(p,p^k)*w[o][i][p^k] ----------------
// per-layer dispatch (fused-3 variant regressed: lost L2 warmth, slower stores)
__global__ __launch_bounds__(256) void expand_kernel(
    const float* __restrict__ w, u16* __restrict__ Wm)
{
    const int t = blockIdx.x * 256 + threadIdx.x;  // 0..262143 = o*512+i
    const int o = t >> 9;
    const int i = t & 511;
    const float* src = w + ((size_t)t << 3);
    const float4 w0 = reinterpret_cast<const float4*>(src)[0];
    const float4 w1 = reinterpret_cast<const float4*>(src)[1];
    const float wv[8] = {w0.x, w0.y, w0.z, w0.w, w1.x, w1.y, w1.z, w1.w};
    #pragma unroll
    for (int kb = 0; kb < 8; ++kb) {
        u16x8 ov;
        #pragma unroll
        for (int p = 0; p < 8; ++p) {
            const int q = p ^ kb;
            ov[p] = f32_to_bf16(cl3_sign(p, q) * wv[q]);
        }
        reinterpret_cast<u16x8*>(Wm)[((size_t)(o * 8 + kb) << 9) + i] = ov;
    }
}

// ---------------- GEMM: barrier-light pipelined, 128x256 tile, BK=64 ----------------
// C[2048,4096] = A[2048,4096] x Bt[4096,4096]^T; grid 16x16 = 256 blocks (1/CU).
// 8 waves (2M x 4N), 64x64 per wave, 16x16x32 bf16 MFMA.
// ONE s_barrier + ONE counted vmcnt per K-tile (wait-then-barrier, proven R3
// ordering). All 16 ds_reads issued up front; compiler inserts counted lgkm
// waits per MFMA cluster; sched_barrier(0) fences the two 16-MFMA clusters;
// setprio gives MFMA-phase waves priority over read-phase waves (T5).
// Tri-buffered LDS (3 x 48KB), prefetch depth 2, steady-state vmcnt(6).
constexpr int BM = 128, BN = 256, BK = 64, KDIM = 4096, NKT = KDIM / BK;
constexpr int ASZ = BM * BK;        // 8192 u16
constexpr int BSZ = BN * BK;        // 16384 u16
constexpr int BUF = ASZ + BSZ;      // 24576 u16 = 48KB

__global__ __launch_bounds__(512, 2) void gemm8_kernel(
    const u16* __restrict__ A,   // [2048,4096] bf16 row-major
    const u16* __restrict__ Bt,  // [4096,4096] bf16, row n = output col
    float*     __restrict__ C,   // [2048,4096] fp32
    u16*       __restrict__ An)  // [2048,4096] bf16 or nullptr
{
    __shared__ __attribute__((aligned(16))) u16 lds[3 * BUF];  // 144KB

    const int tid = threadIdx.x;
    const int l   = tid & 63;
    const int w   = tid >> 6;        // wave 0..7
    const int wr  = w >> 2;          // 0..1
    const int wc  = w & 3;           // 0..3
    const int l8  = l >> 3, l7 = l & 7;
    const int fr  = l & 15, fq = l >> 4;
    const int row0 = blockIdx.y * BM;
    const int col0 = blockIdx.x * BN;

    // ---- staging: one gld_lds = one wave's 8-row group (1KB); T2 swizzle via
    // pre-swizzled GLOBAL source, LDS destination stays linear (rule #21) ----
    auto stageA = [&](int buf, int kt, int q) {   // q in {0,1}
        const int r = (q * 8 + w) * 8 + l8;       // tile row 0..127 (r&7 == l8)
        const u16* src = A + (size_t)(row0 + r) * KDIM + kt + ((l7 ^ l8) << 3);
        gld_lds16(src, &lds[buf * BUF + r * BK + l7 * 8]);
    };
    auto stageB = [&](int buf, int kt, int q) {   // q in {0..3}
        const int r = (q * 8 + w) * 8 + l8;       // tile col 0..255
        const u16* src = Bt + (size_t)(col0 + r) * KDIM + kt + ((l7 ^ l8) << 3);
        gld_lds16(src, &lds[buf * BUF + ASZ + r * BK + l7 * 8]);
    };
    // ---- swizzled fragment reads ----
    auto rdA = [&](int buf, int mi, int ks) -> bf16x8 {
        const int r = wr * 64 + mi * 16 + fr;
        const int c = (ks * 4 + fq) ^ (r & 7);
        return *reinterpret_cast<const bf16x8*>(&lds[buf * BUF + r * BK + c * 8]);
    };
    auto rdB = [&](int buf, int ni, int ks) -> bf16x8 {
        const int r = wc * 64 + ni * 16 + fr;
        const int c = (ks * 4 + fq) ^ (r & 7);
        return *reinterpret_cast<const bf16x8*>(&lds[buf * BUF + ASZ + r * BK + c * 8]);
    };

    f32x4 acc[4][4];
    #pragma unroll
    for (int i = 0; i < 4; ++i)
        #pragma unroll
        for (int j = 0; j < 4; ++j)
            acc[i][j] = f32x4{0.f, 0.f, 0.f, 0.f};

    // ---- prologue: stage tiles 0 and 1 (6 loads each) ----
    stageA(0, 0, 0); stageA(0, 0, 1);
    stageB(0, 0, 0); stageB(0, 0, 1); stageB(0, 0, 2); stageB(0, 0, 3);
    stageA(1, BK, 0); stageA(1, BK, 1);
    stageB(1, BK, 0); stageB(1, BK, 1); stageB(1, BK, 2); stageB(1, BK, 3);
    asm volatile("s_waitcnt vmcnt(6)" ::: "memory");   // tile0 landed (12 -> 6)
    __builtin_amdgcn_s_barrier();

    int cb = 0, nb = 2;
    for (int t = 0; t < NKT; ++t) {
        const int kt2 = (t + 2) * BK;
        const bool pre = (t + 2 < NKT);

        // issue next-next tile staging first (HBM latency hides under this iter)
        if (pre) {
            stageA(nb, kt2, 0); stageA(nb, kt2, 1);
            stageB(nb, kt2, 0); stageB(nb, kt2, 1); stageB(nb, kt2, 2); stageB(nb, kt2, 3);
        }

        // issue ALL fragment reads for this tile; compiler emits counted
        // lgkm waits at each use point (cluster 1 won't wait on a2)
        bf16x8 a[2][2], a2[2][2], b[4][2];
        #pragma unroll
        for (int mi = 0; mi < 2; ++mi)
            #pragma unroll
            for (int ks = 0; ks < 2; ++ks) a[mi][ks] = rdA(cb, mi, ks);
        #pragma unroll
        for (int ni = 0; ni < 4; ++ni)
            #pragma unroll
            for (int ks = 0; ks < 2; ++ks) b[ni][ks] = rdB(cb, ni, ks);
        #pragma unroll
        for (int mi = 0; mi < 2; ++mi)
            #pragma unroll
            for (int ks = 0; ks < 2; ++ks) a2[mi][ks] = rdA(cb, mi + 2, ks);
        __builtin_amdgcn_sched_barrier(0);

        // MFMA cluster 1: acc rows 0-1 (16 MFMA)
        __builtin_amdgcn_s_setprio(1);
        #pragma unroll
        for (int mi = 0; mi < 2; ++mi)
            #pragma unroll
            for (int ni = 0; ni < 4; ++ni)
                #pragma unroll
                for (int ks = 0; ks < 2; ++ks)
                    acc[mi][ni] = __builtin_amdgcn_mfma_f32_16x16x32_bf16(
                        a[mi][ks], b[ni][ks], acc[mi][ni], 0, 0, 0);
        __builtin_amdgcn_s_setprio(0);
        __builtin_amdgcn_sched_barrier(0);

        // MFMA cluster 2: acc rows 2-3 (16 MFMA)
        __builtin_amdgcn_s_setprio(1);
        #pragma unroll
        for (int mi = 0; mi < 2; ++mi)
            #pragma unroll
            for (int ni = 0; ni < 4; ++ni)
                #pragma unroll
                for (int ks = 0; ks < 2; ++ks)
                    acc[mi + 2][ni] = __builtin_amdgcn_mfma_f32_16x16x32_bf16(
                        a2[mi][ks], b[ni][ks], acc[mi + 2][ni], 0, 0, 0);
        __builtin_amdgcn_s_setprio(0);
        __builtin_amdgcn_sched_barrier(0);

        // iter end: per-wave counted drain THEN barrier (cross-wave visibility)
        if (t + 2 < NKT)      { asm volatile("s_waitcnt vmcnt(6)" ::: "memory"); }
        else if (t + 1 < NKT) { asm volatile("s_waitcnt vmcnt(0)" ::: "memory"); }
        __builtin_amdgcn_s_barrier();

        cb = (cb == 2) ? 0 : cb + 1;
        nb = (nb == 2) ? 0 : nb + 1;
    }

    // ---- epilogue: C/D layout col = l&15, row = (l>>4)*4 + v ----
    #pragma unroll
    for (int mi = 0; mi < 4; ++mi) {
        #pragma unroll
        for (int v = 0; v < 4; ++v) {
            const int r = row0 + wr * 64 + mi * 16 + fq * 4 + v;
            const size_t base = ((size_t)r << 12) + col0 + wc * 64 + fr;
            #pragma unroll
            for (int ni = 0; ni < 4; ++ni)
                C[base + ni * 16] = acc[mi][ni][v];
            if (An != nullptr) {
                #pragma unroll
                for (int ni = 0; ni < 4; ++ni)
                    An[base + ni * 16] = f32_to_bf16(acc[mi][ni][v]);
            }
        }
    }
}

// ---------------- launcher ----------------
// ws layout: A0 (16.78MB bf16) | A1 (16.78MB bf16) | Wmat (33.55MB bf16)
extern "C" void kernel_launch(void* const* d_in, const int* in_sizes, int n_in,
                              void* d_out, int out_size, void* d_ws, size_t ws_size,
                              hipStream_t stream) {
    const float* x = (const float*)d_in[0];
    const float* wts[3] = {(const float*)d_in[1], (const float*)d_in[2],
                           (const float*)d_in[3]};
    float* out = (float*)d_out;

    constexpr size_t LAYER = (size_t)2048 * 4096;   // activation elems

    u16* A0 = (u16*)d_ws;
    u16* A1 = A0 + LAYER;
    u16* Wm = A1 + LAYER;

    prep_kernel<<<dim3(8192), dim3(256), 0, stream>>>(x, out, A0);

    u16* Ac = A0;
    u16* Anx = A1;
    for (int L = 0; L < 3; ++L) {
        expand_kernel<<<dim3(1024), dim3(256), 0, stream>>>(wts[L], Wm);
        gemm8_kernel<<<dim3(16, 16), dim3(512), 0, stream>>>(
            Ac, Wm, out + (size_t)(L + 1) * LAYER, (L == 2) ? nullptr : Anx);
        u16* t = Ac; Ac = Anx; Anx = t;
    }
}